// Round 5
// baseline (267.103 us; speedup 1.0000x reference)
//
#include <hip/hip_runtime.h>
#include <hip/hip_bf16.h>

#define HH 128
#define EE 256
#define KK 4
#define RR 8
#define LL 2
#define BB 2
#define SS 1024
#define BT (BB*SS)      // 2048 tokens total
#define NJ (RR+2*HH)    // 264 dbc rows
#define GG 16           // scan chunks per sequence
#define CH (SS/GG)      // 64 timesteps per chunk
#define EPS 1e-5f
#define LOG2E 1.44269504088896f

__device__ __forceinline__ float silu_f(float v) {
    return v / (1.0f + __expf(-v));
}

// ---------------- K1: rmsnorm + in_proj (+bias) -> xz [2048][512] ------------
// (only used for layer 0; later layers get this fused into k_gate<NEXT=1>)
__global__ __launch_bounds__(512) void k_norm_inproj(
    const float* __restrict__ xin, const float* __restrict__ inw,
    const float* __restrict__ inb, const float* __restrict__ nw,
    float* __restrict__ xz)
{
    __shared__ float xn[16][128];
    const int bt0 = blockIdx.x * 16;
    const int tid = threadIdx.x;
    {   // phase A: rmsnorm for 16 tokens, 32 threads per token
        const int t = tid >> 5, g = tid & 31;
        const float4 xv = *(const float4*)(xin + (bt0 + t) * HH + g * 4);
        float ss = xv.x*xv.x + xv.y*xv.y + xv.z*xv.z + xv.w*xv.w;
        #pragma unroll
        for (int m = 16; m >= 1; m >>= 1) ss += __shfl_xor(ss, m);
        const float rs = rsqrtf(ss * (1.0f / HH) + EPS);
        const float4 wv = *(const float4*)(nw + g * 4);
        float4 o;
        o.x = xv.x * rs * wv.x; o.y = xv.y * rs * wv.y;
        o.z = xv.z * rs * wv.z; o.w = xv.w * rs * wv.w;
        *(float4*)(&xn[t][g * 4]) = o;
    }
    __syncthreads();
    // phase B: thread = output column j (512), 16-token accumulators
    const int j = tid;
    float acc[16];
    const float bj = inb[j];
    #pragma unroll
    for (int t = 0; t < 16; t++) acc[t] = bj;
    float w0n = inw[0*512 + j], w1n = inw[1*512 + j];
    float w2n = inw[2*512 + j], w3n = inw[3*512 + j];
    for (int k4 = 0; k4 < 32; k4++) {
        const float w0 = w0n, w1 = w1n, w2 = w2n, w3 = w3n;
        if (k4 < 31) {
            const int k = (k4 + 1) * 4;
            w0n = inw[(k+0)*512 + j]; w1n = inw[(k+1)*512 + j];
            w2n = inw[(k+2)*512 + j]; w3n = inw[(k+3)*512 + j];
        }
        const int k = k4 * 4;
        #pragma unroll
        for (int t = 0; t < 16; t++) {
            const float4 xv = *(const float4*)(&xn[t][k]);
            acc[t] += w0*xv.x + w1*xv.y + w2*xv.z + w3*xv.w;
        }
    }
    #pragma unroll
    for (int t = 0; t < 16; t++) xz[(bt0 + t) * 512 + j] = acc[t];
}

// ---------------- K2: fused conv+silu -> pl_proj -> delta --------------------
// 16-token tiles, 512 threads, grid 128.
// writes xcT [256][2048], BC4 [512][128][8], deltaT [256][2048], sT [256][2048]
__global__ __launch_bounds__(512) void k_fused_cpd(
    const float* __restrict__ xz, const float* __restrict__ cw,
    const float* __restrict__ cb, const float* __restrict__ plw,
    const float* __restrict__ plb, const float* __restrict__ dtw,
    const float* __restrict__ dtb,
    float* __restrict__ xcT, float* __restrict__ BC4,
    float* __restrict__ deltaT, float* __restrict__ sT)
{
    __shared__ float xcb[16][256];
    __shared__ float dbc[8][16];
    const int bt0 = blockIdx.x * 16;
    const int tid = threadIdx.x;
    // Phase C: conv + silu for 16 tokens (each thread: one e, 8 tokens)
    {
        const int e = tid & 255, hf = tid >> 8;
        const int ts = bt0 + hf * 8;
        const float w0 = cw[e*4+0], w1 = cw[e*4+1], w2 = cw[e*4+2], w3 = cw[e*4+3];
        const float bias = cb[e];
        const float* xp = xz + (size_t)ts * 512 + e;
        const bool first = ((ts & 1023) == 0);
        float xm3 = first ? 0.0f : xp[-3*512];
        float xm2 = first ? 0.0f : xp[-2*512];
        float xm1 = first ? 0.0f : xp[-1*512];
        float xcv[8];
        #pragma unroll
        for (int i = 0; i < 8; i++) {
            const float x0 = xp[i*512];
            const float v = bias + w3*x0 + w2*xm1 + w1*xm2 + w0*xm3;
            const float o = silu_f(v);
            xcv[i] = o;
            xcb[hf*8 + i][e] = o;
            xm3 = xm2; xm2 = xm1; xm1 = x0;
        }
        float* orow = xcT + (size_t)e * BT + ts;
        *(float4*)(orow)     = make_float4(xcv[0], xcv[1], xcv[2], xcv[3]);
        *(float4*)(orow + 4) = make_float4(xcv[4], xcv[5], xcv[6], xcv[7]);
    }
    __syncthreads();
    // Phase D: pl_proj (threads 0..263 = output row j)
    if (tid < NJ) {
        const int j = tid;
        float acc[16];
        const float bj = plb[j];
        #pragma unroll
        for (int t = 0; t < 16; t++) acc[t] = bj;
        float w0n = plw[0*NJ + j], w1n = plw[1*NJ + j];
        float w2n = plw[2*NJ + j], w3n = plw[3*NJ + j];
        for (int e4 = 0; e4 < 64; e4++) {
            const float w0 = w0n, w1 = w1n, w2 = w2n, w3 = w3n;
            if (e4 < 63) {
                const int e = (e4 + 1) * 4;
                w0n = plw[(e+0)*NJ + j]; w1n = plw[(e+1)*NJ + j];
                w2n = plw[(e+2)*NJ + j]; w3n = plw[(e+3)*NJ + j];
            }
            const int e = e4 * 4;
            #pragma unroll
            for (int t = 0; t < 16; t++) {
                const float4 xv = *(const float4*)(&xcb[t][e]);
                acc[t] += w0*xv.x + w1*xv.y + w2*xv.z + w3*xv.w;
            }
        }
        if (j < RR) {
            #pragma unroll
            for (int t = 0; t < 16; t++) dbc[j][t] = acc[t];
        } else {
            const int isC = (j >= RR + HH);
            const int nn = isC ? (j - RR - HH) : (j - RR);
            const int tq0 = bt0 >> 2;
            #pragma unroll
            for (int q = 0; q < 4; q++) {
                float* p = BC4 + ((size_t)(tq0 + q) * 128 + nn) * 8 + (isC ? 4 : 0);
                *(float4*)p = make_float4(acc[q*4+0], acc[q*4+1], acc[q*4+2], acc[q*4+3]);
            }
        }
    }
    __syncthreads();
    // Phase E: delta = softplus(dt_proj), s = delta*xc
    {
        const int e = tid & 255, hf = tid >> 8;
        const int ts = bt0 + hf * 8;
        float dv[8];
        const float db = dtb[e];
        #pragma unroll
        for (int i = 0; i < 8; i++) dv[i] = db;
        #pragma unroll
        for (int r = 0; r < RR; r++) {
            const float w = dtw[r*EE + e];
            #pragma unroll
            for (int i = 0; i < 8; i++) dv[i] += w * dbc[r][hf*8 + i];
        }
        float spv[8], sv[8];
        #pragma unroll
        for (int i = 0; i < 8; i++) {
            const float d = dv[i];
            const float sp = (d > 15.0f) ? d : log1pf(__expf(d));
            spv[i] = sp;
            sv[i] = sp * xcb[hf*8 + i][e];
        }
        float* drp = deltaT + (size_t)e * BT + ts;
        *(float4*)(drp)     = make_float4(spv[0], spv[1], spv[2], spv[3]);
        *(float4*)(drp + 4) = make_float4(spv[4], spv[5], spv[6], spv[7]);
        float* srp = sT + (size_t)e * BT + ts;
        *(float4*)(srp)     = make_float4(sv[0], sv[1], sv[2], sv[3]);
        *(float4*)(srp + 4) = make_float4(sv[4], sv[5], sv[6], sv[7]);
    }
}

// ---------------- K3: chunk-local scan, 2 e's per block ----------------------
// grid = B*GG*(EE/2) = 4096, block = 128 (n). Also emits per-chunk delta sums.
__global__ __launch_bounds__(128, 4) void k_scan_local(
    const float* __restrict__ BC4, const float* __restrict__ deltaT,
    const float* __restrict__ sT, const float* __restrict__ Alog,
    float* __restrict__ yT, float* __restrict__ hchain,
    float* __restrict__ dsum)
{
    __shared__ float part[2][16][68];
    __shared__ float ybuf[2][CH];
    const int blk = blockIdx.x;
    const int wgid = (blk & 7) * 512 + (blk >> 3);   // bijective XCD swizzle
    const int eq = wgid & 127;
    const int r0 = wgid >> 7;       // 0..31 = (b,g)
    const int b = r0 >> 4;
    const int g = r0 & 15;
    const int e0 = eq * 2;
    const int n = threadIdx.x;
    const int t0 = g * CH;

    float An0 = -__expf(Alog[(e0+0) * HH + n]) * LOG2E;
    float An1 = -__expf(Alog[(e0+1) * HH + n]) * LOG2E;
    float h0 = 0.0f, h1 = 0.0f, cum0 = 0.0f, cum1 = 0.0f;
    const float* bc = BC4 + ((size_t)((b * 256 + g * 16) * 128 + n)) * 8;
    const float* dr0 = deltaT + (size_t)(e0+0) * BT + b * SS + t0;
    const float* dr1 = deltaT + (size_t)(e0+1) * BT + b * SS + t0;
    const float* sr0 = sT + (size_t)(e0+0) * BT + b * SS + t0;
    const float* sr1 = sT + (size_t)(e0+1) * BT + b * SS + t0;

    float4 pB = *(const float4*)(bc);
    float4 pC = *(const float4*)(bc + 4);
    float4 pd0 = *(const float4*)dr0, pd1 = *(const float4*)dr1;
    float4 ps0 = *(const float4*)sr0, ps1 = *(const float4*)sr1;

    const int tl = n >> 3, jj = n & 7;
    for (int sc = 0; sc < 4; sc++) {
        #pragma unroll
        for (int q = 0; q < 4; q++) {
            const int qq = sc * 4 + q;
            const float4 cB = pB, cC = pC;
            const float4 cd0 = pd0, cd1 = pd1, cs0 = ps0, cs1 = ps1;
            if (qq < 15) {
                const size_t off = (size_t)(qq + 1) * 1024;
                pB = *(const float4*)(bc + off);
                pC = *(const float4*)(bc + off + 4);
                const int t = (qq + 1) * 4;
                pd0 = *(const float4*)(dr0 + t); pd1 = *(const float4*)(dr1 + t);
                ps0 = *(const float4*)(sr0 + t); ps1 = *(const float4*)(sr1 + t);
            }
            float a;
            a = exp2f(cd0.x*An0); h0 = a*h0 + cs0.x*cB.x; part[0][q*4+0][n] = h0*cC.x;
            a = exp2f(cd0.y*An0); h0 = a*h0 + cs0.y*cB.y; part[0][q*4+1][n] = h0*cC.y;
            a = exp2f(cd0.z*An0); h0 = a*h0 + cs0.z*cB.z; part[0][q*4+2][n] = h0*cC.z;
            a = exp2f(cd0.w*An0); h0 = a*h0 + cs0.w*cB.w; part[0][q*4+3][n] = h0*cC.w;
            a = exp2f(cd1.x*An1); h1 = a*h1 + cs1.x*cB.x; part[1][q*4+0][n] = h1*cC.x;
            a = exp2f(cd1.y*An1); h1 = a*h1 + cs1.y*cB.y; part[1][q*4+1][n] = h1*cC.y;
            a = exp2f(cd1.z*An1); h1 = a*h1 + cs1.z*cB.z; part[1][q*4+2][n] = h1*cC.z;
            a = exp2f(cd1.w*An1); h1 = a*h1 + cs1.w*cB.w; part[1][q*4+3][n] = h1*cC.w;
            cum0 += (cd0.x + cd0.y) + (cd0.z + cd0.w);
            cum1 += (cd1.x + cd1.y) + (cd1.z + cd1.w);
        }
        __syncthreads();
        #pragma unroll
        for (int ee = 0; ee < 2; ee++) {
            float s0 = 0, s1 = 0, s2 = 0, s3 = 0;
            #pragma unroll
            for (int i = 0; i < 4; i++) {
                const float4 p = *(const float4*)(&part[ee][tl][jj*16 + i*4]);
                s0 += p.x; s1 += p.y; s2 += p.z; s3 += p.w;
            }
            float r = (s0 + s1) + (s2 + s3);
            r += __shfl_xor(r, 1); r += __shfl_xor(r, 2); r += __shfl_xor(r, 4);
            if (jj == 0) ybuf[ee][sc*16 + tl] = r;
        }
        __syncthreads();
    }
    {
        const int ee = n >> 6, tt = n & 63;
        yT[(size_t)(e0 + ee) * BT + b * SS + t0 + tt] = ybuf[ee][tt];
    }
    hchain[(size_t)(((b * EE + e0 + 0) * GG) + g) * 128 + n] = h0;
    hchain[(size_t)(((b * EE + e0 + 1) * GG) + g) * 128 + n] = h1;
    if (n == 0) {
        dsum[(b * EE + e0 + 0) * GG + g] = cum0;
        dsum[(b * EE + e0 + 1) * GG + g] = cum1;
    }
}

// ---------------- K4: cross-chunk correction (inline combine) ----------------
// grid = B*15*(EE/2) = 3840, block = 128 (n)
__global__ __launch_bounds__(128, 4) void k_scan_fix(
    const float* __restrict__ BC4, const float* __restrict__ deltaT,
    const float* __restrict__ Alog, const float* __restrict__ hchain,
    const float* __restrict__ dsum, float* __restrict__ yT)
{
    __shared__ float part[2][16][68];
    __shared__ float ybuf[2][CH];
    const int blk = blockIdx.x;
    const int wgid = (blk & 7) * 480 + (blk >> 3);   // bijective XCD swizzle
    const int eq = wgid & 127;
    const int r0 = wgid >> 7;       // 0..29
    const int b = r0 / 15;
    const int g = 1 + (r0 % 15);
    const int e0 = eq * 2;
    const int n = threadIdx.x;
    const int t0 = g * CH;

    const float An0 = -__expf(Alog[(e0+0) * HH + n]) * LOG2E;
    const float An1 = -__expf(Alog[(e0+1) * HH + n]) * LOG2E;
    // inline combine: chain h_end across chunks 0..g-1 to get h_start(g)
    float w0 = 0.0f, w1 = 0.0f;
    {
        const size_t hb0 = (size_t)((b * EE + e0 + 0) * GG) * 128 + n;
        const size_t hb1 = (size_t)((b * EE + e0 + 1) * GG) * 128 + n;
        const int db0 = (b * EE + e0 + 0) * GG;
        const int db1 = (b * EE + e0 + 1) * GG;
        for (int gp = 0; gp < g; gp++) {
            const float he0 = hchain[hb0 + (size_t)gp * 128];
            const float he1 = hchain[hb1 + (size_t)gp * 128];
            w0 = exp2f(An0 * dsum[db0 + gp]) * w0 + he0;
            w1 = exp2f(An1 * dsum[db1 + gp]) * w1 + he1;
        }
    }
    float D0 = 0.0f, D1 = 0.0f;
    const float* bc = BC4 + ((size_t)((b * 256 + g * 16) * 128 + n)) * 8;
    const float* dr0 = deltaT + (size_t)(e0+0) * BT + b * SS + t0;
    const float* dr1 = deltaT + (size_t)(e0+1) * BT + b * SS + t0;

    float4 pC = *(const float4*)(bc + 4);
    float4 pd0 = *(const float4*)dr0, pd1 = *(const float4*)dr1;

    const int tl = n >> 3, jj = n & 7;
    for (int sc = 0; sc < 4; sc++) {
        #pragma unroll
        for (int q = 0; q < 4; q++) {
            const int qq = sc * 4 + q;
            const float4 cC = pC;
            const float4 cd0 = pd0, cd1 = pd1;
            if (qq < 15) {
                const size_t off = (size_t)(qq + 1) * 1024;
                pC = *(const float4*)(bc + off + 4);
                const int t = (qq + 1) * 4;
                pd0 = *(const float4*)(dr0 + t); pd1 = *(const float4*)(dr1 + t);
            }
            D0 += cd0.x; part[0][q*4+0][n] = exp2f(An0*D0) * w0 * cC.x;
            D0 += cd0.y; part[0][q*4+1][n] = exp2f(An0*D0) * w0 * cC.y;
            D0 += cd0.z; part[0][q*4+2][n] = exp2f(An0*D0) * w0 * cC.z;
            D0 += cd0.w; part[0][q*4+3][n] = exp2f(An0*D0) * w0 * cC.w;
            D1 += cd1.x; part[1][q*4+0][n] = exp2f(An1*D1) * w1 * cC.x;
            D1 += cd1.y; part[1][q*4+1][n] = exp2f(An1*D1) * w1 * cC.y;
            D1 += cd1.z; part[1][q*4+2][n] = exp2f(An1*D1) * w1 * cC.z;
            D1 += cd1.w; part[1][q*4+3][n] = exp2f(An1*D1) * w1 * cC.w;
        }
        __syncthreads();
        #pragma unroll
        for (int ee = 0; ee < 2; ee++) {
            float s0 = 0, s1 = 0, s2 = 0, s3 = 0;
            #pragma unroll
            for (int i = 0; i < 4; i++) {
                const float4 p = *(const float4*)(&part[ee][tl][jj*16 + i*4]);
                s0 += p.x; s1 += p.y; s2 += p.z; s3 += p.w;
            }
            float r = (s0 + s1) + (s2 + s3);
            r += __shfl_xor(r, 1); r += __shfl_xor(r, 2); r += __shfl_xor(r, 4);
            if (jj == 0) ybuf[ee][sc*16 + tl] = r;
        }
        __syncthreads();
    }
    {
        const int ee = n >> 6, tt = n & 63;
        yT[(size_t)(e0 + ee) * BT + b * SS + t0 + tt] += ybuf[ee][tt];
    }
}

// ---------------- K5: gate + out_proj + residual [+ next rmsnorm+in_proj] ----
// NEXT=1: fuse next layer's rmsnorm + in_proj (writes xznext).
// FINAL=1: fuse final rmsnorm (writes out).
template<int NEXT, int FINAL>
__global__ __launch_bounds__(256) void k_gate(
    const float* __restrict__ yT, const float* __restrict__ xcT,
    const float* __restrict__ xz, const float* __restrict__ Dp,
    const float* __restrict__ ow, const float* __restrict__ ob,
    const float* __restrict__ resin, float* __restrict__ xres,
    const float* __restrict__ nw, const float* __restrict__ inw,
    const float* __restrict__ inb, float* __restrict__ xznext,
    const float* __restrict__ fw, float* __restrict__ out)
{
    __shared__ float gs[16][256];
    __shared__ float rb[16][132];   // part2, then residual rows; col 128 = rs
    const int bt0 = blockIdx.x * 16;
    const int tid = threadIdx.x;
    {   // phase A: g = (y + Dp*xc) * silu(skip)
        const int e = tid;
        const float dp = Dp[e];
        const float* yp = yT + (size_t)e * BT + bt0;
        const float* xp = xcT + (size_t)e * BT + bt0;
        #pragma unroll
        for (int tq = 0; tq < 4; tq++) {
            const float4 y4 = *(const float4*)(yp + tq * 4);
            const float4 x4 = *(const float4*)(xp + tq * 4);
            float sk;
            sk = xz[(size_t)(bt0 + tq*4 + 0) * 512 + 256 + e];
            gs[tq*4+0][e] = (y4.x + dp * x4.x) * silu_f(sk);
            sk = xz[(size_t)(bt0 + tq*4 + 1) * 512 + 256 + e];
            gs[tq*4+1][e] = (y4.y + dp * x4.y) * silu_f(sk);
            sk = xz[(size_t)(bt0 + tq*4 + 2) * 512 + 256 + e];
            gs[tq*4+2][e] = (y4.z + dp * x4.z) * silu_f(sk);
            sk = xz[(size_t)(bt0 + tq*4 + 3) * 512 + 256 + e];
            gs[tq*4+3][e] = (y4.w + dp * x4.w) * silu_f(sk);
        }
    }
    __syncthreads();
    // phase B: out_proj split-K, thread = (j, kh)
    const int j = tid & 127;
    const int kh = tid >> 7;
    {
        float acc[16];
        #pragma unroll
        for (int t = 0; t < 16; t++) acc[t] = 0.0f;
        const int eb = kh * 128;
        float w0n = ow[(eb+0)*HH + j], w1n = ow[(eb+1)*HH + j];
        float w2n = ow[(eb+2)*HH + j], w3n = ow[(eb+3)*HH + j];
        for (int e4 = 0; e4 < 32; e4++) {
            const float w0 = w0n, w1 = w1n, w2 = w2n, w3 = w3n;
            if (e4 < 31) {
                const int e = eb + (e4 + 1) * 4;
                w0n = ow[(e+0)*HH + j]; w1n = ow[(e+1)*HH + j];
                w2n = ow[(e+2)*HH + j]; w3n = ow[(e+3)*HH + j];
            }
            const int e = eb + e4 * 4;
            #pragma unroll
            for (int t = 0; t < 16; t++) {
                const float4 g4 = *(const float4*)(&gs[t][e]);
                acc[t] += w0*g4.x + w1*g4.y + w2*g4.z + w3*g4.w;
            }
        }
        if (kh == 1) {
            #pragma unroll
            for (int t = 0; t < 16; t++) rb[t][j] = acc[t];
        }
        __syncthreads();
        if (kh == 0) {
            const float bj = ob[j];
            #pragma unroll
            for (int t = 0; t < 16; t++) {
                const float r = acc[t] + rb[t][j] + bj
                              + resin[(size_t)(bt0 + t) * HH + j];
                if (!FINAL) xres[(size_t)(bt0 + t) * HH + j] = r;
                rb[t][j] = r;   // in-place: this slot was read by this thread
            }
        }
    }
    if (NEXT || FINAL) {
        __syncthreads();
        // rmsnorm over residual rows: 16 threads per token
        const int t = tid >> 4, g16 = tid & 15;
        const float4 a = *(const float4*)(&rb[t][g16*8]);
        const float4 c = *(const float4*)(&rb[t][g16*8 + 4]);
        float ss = a.x*a.x + a.y*a.y + a.z*a.z + a.w*a.w
                 + c.x*c.x + c.y*c.y + c.z*c.z + c.w*c.w;
        ss += __shfl_xor(ss, 1); ss += __shfl_xor(ss, 2);
        ss += __shfl_xor(ss, 4); ss += __shfl_xor(ss, 8);
        if (g16 == 0) rb[t][128] = rsqrtf(ss * (1.0f / HH) + EPS);
        __syncthreads();
    }
    if (FINAL) {
        const int jc = tid & 127, th = tid >> 7;
        const float fwj = fw[jc];
        #pragma unroll
        for (int i = 0; i < 8; i++) {
            const int t = th * 8 + i;
            out[(size_t)(bt0 + t) * HH + jc] = rb[t][jc] * rb[t][128] * fwj;
        }
    }
    if (NEXT) {
        // next layer in_proj: each thread handles columns tid and tid+256
        const int j0 = tid, j1 = tid + 256;
        float acc0[16], acc1[16];
        #pragma unroll
        for (int t = 0; t < 16; t++) { acc0[t] = 0.0f; acc1[t] = 0.0f; }
        for (int k4 = 0; k4 < 32; k4++) {
            const int k = k4 * 4;
            const float4 nv = *(const float4*)(nw + k);
            const float u0 = inw[(k+0)*512 + j0] * nv.x;
            const float u1 = inw[(k+1)*512 + j0] * nv.y;
            const float u2 = inw[(k+2)*512 + j0] * nv.z;
            const float u3 = inw[(k+3)*512 + j0] * nv.w;
            const float v0 = inw[(k+0)*512 + j1] * nv.x;
            const float v1 = inw[(k+1)*512 + j1] * nv.y;
            const float v2 = inw[(k+2)*512 + j1] * nv.z;
            const float v3 = inw[(k+3)*512 + j1] * nv.w;
            #pragma unroll
            for (int t = 0; t < 16; t++) {
                const float4 xv = *(const float4*)(&rb[t][k]);
                acc0[t] += u0*xv.x + u1*xv.y + u2*xv.z + u3*xv.w;
                acc1[t] += v0*xv.x + v1*xv.y + v2*xv.z + v3*xv.w;
            }
        }
        const float b0 = inb[j0], b1 = inb[j1];
        #pragma unroll
        for (int t = 0; t < 16; t++) {
            const float rs = rb[t][128];
            xznext[(size_t)(bt0 + t) * 512 + j0] = acc0[t] * rs + b0;
            xznext[(size_t)(bt0 + t) * 512 + j1] = acc1[t] * rs + b1;
        }
    }
}

extern "C" void kernel_launch(void* const* d_in, const int* in_sizes, int n_in,
                              void* d_out, int out_size, void* d_ws, size_t ws_size,
                              hipStream_t stream)
{
    const float* x      = (const float*)d_in[0];
    const float* in_w   = (const float*)d_in[1];
    const float* in_b   = (const float*)d_in[2];
    const float* out_w  = (const float*)d_in[3];
    const float* out_b  = (const float*)d_in[4];
    const float* pl_w   = (const float*)d_in[5];
    const float* pl_b   = (const float*)d_in[6];
    const float* dt_w   = (const float*)d_in[7];
    const float* dt_b   = (const float*)d_in[8];
    const float* conv_w = (const float*)d_in[9];
    const float* conv_b = (const float*)d_in[10];
    const float* A_log  = (const float*)d_in[11];
    const float* Dp     = (const float*)d_in[12];
    const float* norm_w = (const float*)d_in[13];
    const float* fnw    = (const float*)d_in[14];

    float* ws     = (float*)d_ws;
    float* xres   = ws;                        // 262144
    float* xz     = xres   + 262144;           // 1048576
    float* xcT    = xz     + 1048576;          // 524288
    float* BC4    = xcT    + 524288;           // 524288
    float* deltaT = BC4    + 524288;           // 524288
    float* sT     = deltaT + 524288;           // 524288
    float* yT     = sT     + 524288;           // 524288
    float* hchain = yT     + 524288;           // 1048576
    float* dsum   = hchain + 1048576;          // 8192   (total ~20 MB)

    // ---- layer 0 ----
    k_norm_inproj<<<BT/16, 512, 0, stream>>>(x, in_w, in_b, norm_w, xz);
    k_fused_cpd<<<BT/16, 512, 0, stream>>>(
        xz, conv_w, conv_b, pl_w, pl_b, dt_w, dt_b, xcT, BC4, deltaT, sT);
    k_scan_local<<<BB*GG*(EE/2), 128, 0, stream>>>(
        BC4, deltaT, sT, A_log, yT, hchain, dsum);
    k_scan_fix<<<BB*(GG-1)*(EE/2), 128, 0, stream>>>(
        BC4, deltaT, A_log, hchain, dsum, yT);
    k_gate<1, 0><<<BT/16, 256, 0, stream>>>(
        yT, xcT, xz, Dp, out_w, out_b, x, xres,
        norm_w + HH, in_w + (size_t)HH*2*EE, in_b + 2*EE, xz,
        nullptr, nullptr);

    // ---- layer 1 ----
    k_fused_cpd<<<BT/16, 512, 0, stream>>>(
        xz, conv_w + EE*KK, conv_b + EE, pl_w + (size_t)EE*NJ, pl_b + NJ,
        dt_w + RR*EE, dt_b + EE, xcT, BC4, deltaT, sT);
    k_scan_local<<<BB*GG*(EE/2), 128, 0, stream>>>(
        BC4, deltaT, sT, A_log + (size_t)EE*HH, yT, hchain, dsum);
    k_scan_fix<<<BB*(GG-1)*(EE/2), 128, 0, stream>>>(
        BC4, deltaT, A_log + (size_t)EE*HH, hchain, dsum, yT);
    k_gate<0, 1><<<BT/16, 256, 0, stream>>>(
        yT, xcT, xz, Dp + EE, out_w + (size_t)EE*HH, out_b + HH, xres, xres,
        nullptr, nullptr, nullptr, nullptr,
        fnw, (float*)d_out);
}

// Round 6
// 231.323 us; speedup vs baseline: 1.1547x; 1.1547x over previous
//
#include <hip/hip_runtime.h>
#include <hip/hip_bf16.h>

#define HH 128
#define EE 256
#define KK 4
#define RR 8
#define LL 2
#define BB 2
#define SS 1024
#define BT (BB*SS)      // 2048 tokens total
#define NJ (RR+2*HH)    // 264 dbc rows
#define GG 16           // scan chunks per sequence
#define CH (SS/GG)      // 64 timesteps per chunk
#define EPS 1e-5f
#define LOG2E 1.44269504088896f

__device__ __forceinline__ float silu_f(float v) {
    return v / (1.0f + __expf(-v));
}

// ---------------- K0: Wdt = pl_w[:, :8] @ dt_w ; bdt = pl_b[:8]@dt_w + dt_b --
// grid = 8 (layer, quarter), block = 256
__global__ __launch_bounds__(256) void k_wdt(
    const float* __restrict__ plw, const float* __restrict__ plb,
    const float* __restrict__ dtw, const float* __restrict__ dtb,
    float* __restrict__ Wdt, float* __restrict__ bdt)
{
    const int l = blockIdx.x >> 2, q = blockIdx.x & 3;
    const int j = threadIdx.x;
    const float* dtwl = dtw + (size_t)l * RR * EE;
    const float* plwl = plw + (size_t)l * EE * NJ;
    float wr[RR];
    #pragma unroll
    for (int r = 0; r < RR; r++) wr[r] = dtwl[r * EE + j];
    float* Wl = Wdt + (size_t)l * EE * EE;
    for (int e = q * 64; e < q * 64 + 64; e++) {
        float a = 0.0f;
        #pragma unroll
        for (int r = 0; r < RR; r++) a += plwl[(size_t)e * NJ + r] * wr[r];
        Wl[(size_t)e * EE + j] = a;
    }
    if (q == 0) {
        float a = dtb[l * EE + j];
        #pragma unroll
        for (int r = 0; r < RR; r++) a += plb[l * NJ + r] * wr[r];
        bdt[l * EE + j] = a;
    }
}

// ---------------- K1: rmsnorm + in_proj (+bias) -> xz [2048][512] ------------
// 8-token tiles, grid 256, block 512
__global__ __launch_bounds__(512) void k_norm_inproj(
    const float* __restrict__ xin, const float* __restrict__ inw,
    const float* __restrict__ inb, const float* __restrict__ nw,
    float* __restrict__ xz)
{
    __shared__ float xn[8][128];
    const int bt0 = blockIdx.x * 8;
    const int tid = threadIdx.x;
    {   // phase A: rmsnorm, one wave per token, 2 elems/lane
        const int t = tid >> 6, lane = tid & 63;
        const float2 xv = *(const float2*)(xin + (size_t)(bt0 + t) * HH + lane * 2);
        float ss = xv.x*xv.x + xv.y*xv.y;
        #pragma unroll
        for (int m = 32; m >= 1; m >>= 1) ss += __shfl_xor(ss, m);
        const float rs = rsqrtf(ss * (1.0f / HH) + EPS);
        const float2 wv = *(const float2*)(nw + lane * 2);
        xn[t][lane*2+0] = xv.x * rs * wv.x;
        xn[t][lane*2+1] = xv.y * rs * wv.y;
    }
    __syncthreads();
    // phase B: thread = output column j (512), 8-token accumulators
    const int j = tid;
    float acc[8];
    const float bj = inb[j];
    #pragma unroll
    for (int t = 0; t < 8; t++) acc[t] = bj;
    float w0n = inw[0*512 + j], w1n = inw[1*512 + j];
    float w2n = inw[2*512 + j], w3n = inw[3*512 + j];
    for (int k4 = 0; k4 < 32; k4++) {
        const float w0 = w0n, w1 = w1n, w2 = w2n, w3 = w3n;
        if (k4 < 31) {
            const int k = (k4 + 1) * 4;
            w0n = inw[(k+0)*512 + j]; w1n = inw[(k+1)*512 + j];
            w2n = inw[(k+2)*512 + j]; w3n = inw[(k+3)*512 + j];
        }
        const int k = k4 * 4;
        #pragma unroll
        for (int t = 0; t < 8; t++) {
            const float4 xv = *(const float4*)(&xn[t][k]);
            acc[t] += w0*xv.x + w1*xv.y + w2*xv.z + w3*xv.w;
        }
    }
    #pragma unroll
    for (int t = 0; t < 8; t++) xz[(size_t)(bt0 + t) * 512 + j] = acc[t];
}

// ---------------- K2: conv+silu, then B/C-proj and delta-proj in parallel ----
// 8-token tiles, grid 256, block 512.
// path 0 (tid<256): B/C columns -> BC4.  path 1: delta via Wdt -> deltaT, sT.
__global__ __launch_bounds__(512) void k_cbd(
    const float* __restrict__ xz, const float* __restrict__ cw,
    const float* __restrict__ cb, const float* __restrict__ plw,
    const float* __restrict__ plb, const float* __restrict__ Wdt,
    const float* __restrict__ bdt,
    float* __restrict__ xcT, float* __restrict__ BC4,
    float* __restrict__ deltaT, float* __restrict__ sT)
{
    __shared__ float xcb[8][256];
    const int bt0 = blockIdx.x * 8;
    const int tid = threadIdx.x;
    {   // conv + silu: (e, half) does 4 tokens
        const int e = tid & 255, hf = tid >> 8;
        const int ts = bt0 + hf * 4;
        const float w0 = cw[e*4+0], w1 = cw[e*4+1], w2 = cw[e*4+2], w3 = cw[e*4+3];
        const float bias = cb[e];
        const float* xp = xz + (size_t)ts * 512 + e;
        const bool first = ((ts & (SS-1)) == 0);
        float xm3 = first ? 0.0f : xp[-3*512];
        float xm2 = first ? 0.0f : xp[-2*512];
        float xm1 = first ? 0.0f : xp[-1*512];
        float xcv[4];
        #pragma unroll
        for (int i = 0; i < 4; i++) {
            const float x0 = xp[i*512];
            const float v = bias + w3*x0 + w2*xm1 + w1*xm2 + w0*xm3;
            const float o = silu_f(v);
            xcv[i] = o;
            xcb[hf*4 + i][e] = o;
            xm3 = xm2; xm2 = xm1; xm1 = x0;
        }
        *(float4*)(xcT + (size_t)e * BT + ts) =
            make_float4(xcv[0], xcv[1], xcv[2], xcv[3]);
    }
    __syncthreads();
    const int j = tid & 255, path = tid >> 8;
    if (path == 0) {
        // B/C projection: column RR + j of pl_w
        const int nn = j & 127, isC = j >> 7;
        const float* wp = plw + RR + isC * HH + nn;  // [e*NJ]
        float acc[8];
        const float bj = plb[RR + isC * HH + nn];
        #pragma unroll
        for (int t = 0; t < 8; t++) acc[t] = bj;
        float w0n = wp[0*NJ], w1n = wp[1*NJ], w2n = wp[2*NJ], w3n = wp[3*NJ];
        for (int e4 = 0; e4 < 64; e4++) {
            const float w0 = w0n, w1 = w1n, w2 = w2n, w3 = w3n;
            if (e4 < 63) {
                const int e = (e4 + 1) * 4;
                w0n = wp[(size_t)(e+0)*NJ]; w1n = wp[(size_t)(e+1)*NJ];
                w2n = wp[(size_t)(e+2)*NJ]; w3n = wp[(size_t)(e+3)*NJ];
            }
            const int e = e4 * 4;
            #pragma unroll
            for (int t = 0; t < 8; t++) {
                const float4 xv = *(const float4*)(&xcb[t][e]);
                acc[t] += w0*xv.x + w1*xv.y + w2*xv.z + w3*xv.w;
            }
        }
        const int tq0 = bt0 >> 2;
        float* p0 = BC4 + ((size_t)tq0 * 128 + nn) * 8 + isC * 4;
        *(float4*)p0 = make_float4(acc[0], acc[1], acc[2], acc[3]);
        float* p1 = BC4 + ((size_t)(tq0 + 1) * 128 + nn) * 8 + isC * 4;
        *(float4*)p1 = make_float4(acc[4], acc[5], acc[6], acc[7]);
    } else {
        // delta projection via combined Wdt
        const float* wp = Wdt + j;                    // [e*EE]
        float acc[8];
        const float bj = bdt[j];
        #pragma unroll
        for (int t = 0; t < 8; t++) acc[t] = bj;
        float w0n = wp[0*EE], w1n = wp[1*EE], w2n = wp[2*EE], w3n = wp[3*EE];
        for (int e4 = 0; e4 < 64; e4++) {
            const float w0 = w0n, w1 = w1n, w2 = w2n, w3 = w3n;
            if (e4 < 63) {
                const int e = (e4 + 1) * 4;
                w0n = wp[(size_t)(e+0)*EE]; w1n = wp[(size_t)(e+1)*EE];
                w2n = wp[(size_t)(e+2)*EE]; w3n = wp[(size_t)(e+3)*EE];
            }
            const int e = e4 * 4;
            #pragma unroll
            for (int t = 0; t < 8; t++) {
                const float4 xv = *(const float4*)(&xcb[t][e]);
                acc[t] += w0*xv.x + w1*xv.y + w2*xv.z + w3*xv.w;
            }
        }
        float spv[8], sv[8];
        #pragma unroll
        for (int t = 0; t < 8; t++) {
            const float d = acc[t];
            const float sp = (d > 15.0f) ? d : log1pf(__expf(d));
            spv[t] = sp;
            sv[t] = sp * xcb[t][j];
        }
        float* drp = deltaT + (size_t)j * BT + bt0;
        *(float4*)(drp)     = make_float4(spv[0], spv[1], spv[2], spv[3]);
        *(float4*)(drp + 4) = make_float4(spv[4], spv[5], spv[6], spv[7]);
        float* srp = sT + (size_t)j * BT + bt0;
        *(float4*)(srp)     = make_float4(sv[0], sv[1], sv[2], sv[3]);
        *(float4*)(srp + 4) = make_float4(sv[4], sv[5], sv[6], sv[7]);
    }
}

// ---------------- K3: chunk-local scan, 2 e's per block ----------------------
// grid = B*GG*(EE/2) = 4096, block = 128 (n). Also emits per-chunk delta sums.
__global__ __launch_bounds__(128, 4) void k_scan_local(
    const float* __restrict__ BC4, const float* __restrict__ deltaT,
    const float* __restrict__ sT, const float* __restrict__ Alog,
    float* __restrict__ yT, float* __restrict__ hchain,
    float* __restrict__ dsum)
{
    __shared__ float part[2][16][68];
    __shared__ float ybuf[2][CH];
    const int blk = blockIdx.x;
    const int wgid = (blk & 7) * 512 + (blk >> 3);   // bijective XCD swizzle
    const int eq = wgid & 127;
    const int r0 = wgid >> 7;       // 0..31 = (b,g)
    const int b = r0 >> 4;
    const int g = r0 & 15;
    const int e0 = eq * 2;
    const int n = threadIdx.x;
    const int t0 = g * CH;

    float An0 = -__expf(Alog[(e0+0) * HH + n]) * LOG2E;
    float An1 = -__expf(Alog[(e0+1) * HH + n]) * LOG2E;
    float h0 = 0.0f, h1 = 0.0f, cum0 = 0.0f, cum1 = 0.0f;
    const float* bc = BC4 + ((size_t)((b * 256 + g * 16) * 128 + n)) * 8;
    const float* dr0 = deltaT + (size_t)(e0+0) * BT + b * SS + t0;
    const float* dr1 = deltaT + (size_t)(e0+1) * BT + b * SS + t0;
    const float* sr0 = sT + (size_t)(e0+0) * BT + b * SS + t0;
    const float* sr1 = sT + (size_t)(e0+1) * BT + b * SS + t0;

    float4 pB = *(const float4*)(bc);
    float4 pC = *(const float4*)(bc + 4);
    float4 pd0 = *(const float4*)dr0, pd1 = *(const float4*)dr1;
    float4 ps0 = *(const float4*)sr0, ps1 = *(const float4*)sr1;

    const int tl = n >> 3, jj = n & 7;
    for (int sc = 0; sc < 4; sc++) {
        #pragma unroll
        for (int q = 0; q < 4; q++) {
            const int qq = sc * 4 + q;
            const float4 cB = pB, cC = pC;
            const float4 cd0 = pd0, cd1 = pd1, cs0 = ps0, cs1 = ps1;
            if (qq < 15) {
                const size_t off = (size_t)(qq + 1) * 1024;
                pB = *(const float4*)(bc + off);
                pC = *(const float4*)(bc + off + 4);
                const int t = (qq + 1) * 4;
                pd0 = *(const float4*)(dr0 + t); pd1 = *(const float4*)(dr1 + t);
                ps0 = *(const float4*)(sr0 + t); ps1 = *(const float4*)(sr1 + t);
            }
            float a;
            a = exp2f(cd0.x*An0); h0 = a*h0 + cs0.x*cB.x; part[0][q*4+0][n] = h0*cC.x;
            a = exp2f(cd0.y*An0); h0 = a*h0 + cs0.y*cB.y; part[0][q*4+1][n] = h0*cC.y;
            a = exp2f(cd0.z*An0); h0 = a*h0 + cs0.z*cB.z; part[0][q*4+2][n] = h0*cC.z;
            a = exp2f(cd0.w*An0); h0 = a*h0 + cs0.w*cB.w; part[0][q*4+3][n] = h0*cC.w;
            a = exp2f(cd1.x*An1); h1 = a*h1 + cs1.x*cB.x; part[1][q*4+0][n] = h1*cC.x;
            a = exp2f(cd1.y*An1); h1 = a*h1 + cs1.y*cB.y; part[1][q*4+1][n] = h1*cC.y;
            a = exp2f(cd1.z*An1); h1 = a*h1 + cs1.z*cB.z; part[1][q*4+2][n] = h1*cC.z;
            a = exp2f(cd1.w*An1); h1 = a*h1 + cs1.w*cB.w; part[1][q*4+3][n] = h1*cC.w;
            cum0 += (cd0.x + cd0.y) + (cd0.z + cd0.w);
            cum1 += (cd1.x + cd1.y) + (cd1.z + cd1.w);
        }
        __syncthreads();
        #pragma unroll
        for (int ee = 0; ee < 2; ee++) {
            float s0 = 0, s1 = 0, s2 = 0, s3 = 0;
            #pragma unroll
            for (int i = 0; i < 4; i++) {
                const float4 p = *(const float4*)(&part[ee][tl][jj*16 + i*4]);
                s0 += p.x; s1 += p.y; s2 += p.z; s3 += p.w;
            }
            float r = (s0 + s1) + (s2 + s3);
            r += __shfl_xor(r, 1); r += __shfl_xor(r, 2); r += __shfl_xor(r, 4);
            if (jj == 0) ybuf[ee][sc*16 + tl] = r;
        }
        __syncthreads();
    }
    {
        const int ee = n >> 6, tt = n & 63;
        yT[(size_t)(e0 + ee) * BT + b * SS + t0 + tt] = ybuf[ee][tt];
    }
    hchain[(size_t)(((b * EE + e0 + 0) * GG) + g) * 128 + n] = h0;
    hchain[(size_t)(((b * EE + e0 + 1) * GG) + g) * 128 + n] = h1;
    if (n == 0) {
        dsum[(b * EE + e0 + 0) * GG + g] = cum0;
        dsum[(b * EE + e0 + 1) * GG + g] = cum1;
    }
}

// ---------------- K4: cross-chunk correction (inline combine) ----------------
// grid = B*15*(EE/2) = 3840, block = 128 (n)
__global__ __launch_bounds__(128, 4) void k_scan_fix(
    const float* __restrict__ BC4, const float* __restrict__ deltaT,
    const float* __restrict__ Alog, const float* __restrict__ hchain,
    const float* __restrict__ dsum, float* __restrict__ yT)
{
    __shared__ float part[2][16][68];
    __shared__ float ybuf[2][CH];
    const int blk = blockIdx.x;
    const int wgid = (blk & 7) * 480 + (blk >> 3);   // bijective XCD swizzle
    const int eq = wgid & 127;
    const int r0 = wgid >> 7;       // 0..29
    const int b = r0 / 15;
    const int g = 1 + (r0 % 15);
    const int e0 = eq * 2;
    const int n = threadIdx.x;
    const int t0 = g * CH;

    const float An0 = -__expf(Alog[(e0+0) * HH + n]) * LOG2E;
    const float An1 = -__expf(Alog[(e0+1) * HH + n]) * LOG2E;
    float w0 = 0.0f, w1 = 0.0f;
    {
        const size_t hb0 = (size_t)((b * EE + e0 + 0) * GG) * 128 + n;
        const size_t hb1 = (size_t)((b * EE + e0 + 1) * GG) * 128 + n;
        const int db0 = (b * EE + e0 + 0) * GG;
        const int db1 = (b * EE + e0 + 1) * GG;
        for (int gp = 0; gp < g; gp++) {
            const float he0 = hchain[hb0 + (size_t)gp * 128];
            const float he1 = hchain[hb1 + (size_t)gp * 128];
            w0 = exp2f(An0 * dsum[db0 + gp]) * w0 + he0;
            w1 = exp2f(An1 * dsum[db1 + gp]) * w1 + he1;
        }
    }
    float D0 = 0.0f, D1 = 0.0f;
    const float* bc = BC4 + ((size_t)((b * 256 + g * 16) * 128 + n)) * 8;
    const float* dr0 = deltaT + (size_t)(e0+0) * BT + b * SS + t0;
    const float* dr1 = deltaT + (size_t)(e0+1) * BT + b * SS + t0;

    float4 pC = *(const float4*)(bc + 4);
    float4 pd0 = *(const float4*)dr0, pd1 = *(const float4*)dr1;

    const int tl = n >> 3, jj = n & 7;
    for (int sc = 0; sc < 4; sc++) {
        #pragma unroll
        for (int q = 0; q < 4; q++) {
            const int qq = sc * 4 + q;
            const float4 cC = pC;
            const float4 cd0 = pd0, cd1 = pd1;
            if (qq < 15) {
                const size_t off = (size_t)(qq + 1) * 1024;
                pC = *(const float4*)(bc + off + 4);
                const int t = (qq + 1) * 4;
                pd0 = *(const float4*)(dr0 + t); pd1 = *(const float4*)(dr1 + t);
            }
            D0 += cd0.x; part[0][q*4+0][n] = exp2f(An0*D0) * w0 * cC.x;
            D0 += cd0.y; part[0][q*4+1][n] = exp2f(An0*D0) * w0 * cC.y;
            D0 += cd0.z; part[0][q*4+2][n] = exp2f(An0*D0) * w0 * cC.z;
            D0 += cd0.w; part[0][q*4+3][n] = exp2f(An0*D0) * w0 * cC.w;
            D1 += cd1.x; part[1][q*4+0][n] = exp2f(An1*D1) * w1 * cC.x;
            D1 += cd1.y; part[1][q*4+1][n] = exp2f(An1*D1) * w1 * cC.y;
            D1 += cd1.z; part[1][q*4+2][n] = exp2f(An1*D1) * w1 * cC.z;
            D1 += cd1.w; part[1][q*4+3][n] = exp2f(An1*D1) * w1 * cC.w;
        }
        __syncthreads();
        #pragma unroll
        for (int ee = 0; ee < 2; ee++) {
            float s0 = 0, s1 = 0, s2 = 0, s3 = 0;
            #pragma unroll
            for (int i = 0; i < 4; i++) {
                const float4 p = *(const float4*)(&part[ee][tl][jj*16 + i*4]);
                s0 += p.x; s1 += p.y; s2 += p.z; s3 += p.w;
            }
            float r = (s0 + s1) + (s2 + s3);
            r += __shfl_xor(r, 1); r += __shfl_xor(r, 2); r += __shfl_xor(r, 4);
            if (jj == 0) ybuf[ee][sc*16 + tl] = r;
        }
        __syncthreads();
    }
    {
        const int ee = n >> 6, tt = n & 63;
        yT[(size_t)(e0 + ee) * BT + b * SS + t0 + tt] += ybuf[ee][tt];
    }
}

// ---------------- K5: gate + out_proj + residual -> xres ---------------------
// 8-token tiles, grid 256, block 256
__global__ __launch_bounds__(256) void k_gate(
    const float* __restrict__ yT, const float* __restrict__ xcT,
    const float* __restrict__ xz, const float* __restrict__ Dp,
    const float* __restrict__ ow, const float* __restrict__ ob,
    const float* __restrict__ resin, float* __restrict__ xres)
{
    __shared__ float gs[8][256];
    __shared__ float p2[8][128];
    const int bt0 = blockIdx.x * 8;
    const int tid = threadIdx.x;
    {   // phase A: g = (y + Dp*xc) * silu(skip)
        const int e = tid;
        const float dp = Dp[e];
        const float* yp = yT + (size_t)e * BT + bt0;
        const float* xp = xcT + (size_t)e * BT + bt0;
        #pragma unroll
        for (int tq = 0; tq < 2; tq++) {
            const float4 y4 = *(const float4*)(yp + tq * 4);
            const float4 x4 = *(const float4*)(xp + tq * 4);
            float sk;
            sk = xz[(size_t)(bt0 + tq*4 + 0) * 512 + 256 + e];
            gs[tq*4+0][e] = (y4.x + dp * x4.x) * silu_f(sk);
            sk = xz[(size_t)(bt0 + tq*4 + 1) * 512 + 256 + e];
            gs[tq*4+1][e] = (y4.y + dp * x4.y) * silu_f(sk);
            sk = xz[(size_t)(bt0 + tq*4 + 2) * 512 + 256 + e];
            gs[tq*4+2][e] = (y4.z + dp * x4.z) * silu_f(sk);
            sk = xz[(size_t)(bt0 + tq*4 + 3) * 512 + 256 + e];
            gs[tq*4+3][e] = (y4.w + dp * x4.w) * silu_f(sk);
        }
    }
    __syncthreads();
    // phase B: out_proj split-K, thread = (j, kh)
    const int j = tid & 127;
    const int kh = tid >> 7;
    float acc[8];
    #pragma unroll
    for (int t = 0; t < 8; t++) acc[t] = 0.0f;
    const int eb = kh * 128;
    float w0n = ow[(eb+0)*HH + j], w1n = ow[(eb+1)*HH + j];
    float w2n = ow[(eb+2)*HH + j], w3n = ow[(eb+3)*HH + j];
    for (int e4 = 0; e4 < 32; e4++) {
        const float w0 = w0n, w1 = w1n, w2 = w2n, w3 = w3n;
        if (e4 < 31) {
            const int e = eb + (e4 + 1) * 4;
            w0n = ow[(e+0)*HH + j]; w1n = ow[(e+1)*HH + j];
            w2n = ow[(e+2)*HH + j]; w3n = ow[(e+3)*HH + j];
        }
        const int e = eb + e4 * 4;
        #pragma unroll
        for (int t = 0; t < 8; t++) {
            const float4 g4 = *(const float4*)(&gs[t][e]);
            acc[t] += w0*g4.x + w1*g4.y + w2*g4.z + w3*g4.w;
        }
    }
    if (kh == 1) {
        #pragma unroll
        for (int t = 0; t < 8; t++) p2[t][j] = acc[t];
    }
    __syncthreads();
    if (kh == 0) {
        const float bj = ob[j];
        #pragma unroll
        for (int t = 0; t < 8; t++) {
            const float r = acc[t] + p2[t][j] + bj
                          + resin[(size_t)(bt0 + t) * HH + j];
            xres[(size_t)(bt0 + t) * HH + j] = r;
        }
    }
}

// ---------------- K6: final rmsnorm -> d_out ---------------------------------
// 8-token tiles, grid 256, block 512
__global__ __launch_bounds__(512) void k_finalnorm(
    const float* __restrict__ xres, const float* __restrict__ fw,
    float* __restrict__ out)
{
    const int bt0 = blockIdx.x * 8;
    const int tid = threadIdx.x;
    const int t = tid >> 6, lane = tid & 63;
    const float2 v = *(const float2*)(xres + (size_t)(bt0 + t) * HH + lane * 2);
    float ss = v.x*v.x + v.y*v.y;
    #pragma unroll
    for (int m = 32; m >= 1; m >>= 1) ss += __shfl_xor(ss, m);
    const float rs = rsqrtf(ss * (1.0f / HH) + EPS);
    const float2 w = *(const float2*)(fw + lane * 2);
    float2 o; o.x = v.x * rs * w.x; o.y = v.y * rs * w.y;
    *(float2*)(out + (size_t)(bt0 + t) * HH + lane * 2) = o;
}

extern "C" void kernel_launch(void* const* d_in, const int* in_sizes, int n_in,
                              void* d_out, int out_size, void* d_ws, size_t ws_size,
                              hipStream_t stream)
{
    const float* x      = (const float*)d_in[0];
    const float* in_w   = (const float*)d_in[1];
    const float* in_b   = (const float*)d_in[2];
    const float* out_w  = (const float*)d_in[3];
    const float* out_b  = (const float*)d_in[4];
    const float* pl_w   = (const float*)d_in[5];
    const float* pl_b   = (const float*)d_in[6];
    const float* dt_w   = (const float*)d_in[7];
    const float* dt_b   = (const float*)d_in[8];
    const float* conv_w = (const float*)d_in[9];
    const float* conv_b = (const float*)d_in[10];
    const float* A_log  = (const float*)d_in[11];
    const float* Dp     = (const float*)d_in[12];
    const float* norm_w = (const float*)d_in[13];
    const float* fnw    = (const float*)d_in[14];

    float* ws     = (float*)d_ws;
    float* xres   = ws;                        // 262144
    float* xz     = xres   + 262144;           // 1048576
    float* xcT    = xz     + 1048576;          // 524288
    float* BC4    = xcT    + 524288;           // 524288
    float* deltaT = BC4    + 524288;           // 524288
    float* sT     = deltaT + 524288;           // 524288
    float* yT     = sT     + 524288;           // 524288
    float* hchain = yT     + 524288;           // 1048576
    float* dsum   = hchain + 1048576;          // 8192
    float* Wdt    = dsum   + 8192;             // 2*256*256 = 131072
    float* bdt    = Wdt    + 131072;           // 512    (total ~21 MB)

    k_wdt<<<2*4, 256, 0, stream>>>(pl_w, pl_b, dt_w, dt_b, Wdt, bdt);

    for (int l = 0; l < LL; l++) {
        const float* resin = (l == 0) ? x : xres;
        k_norm_inproj<<<BT/8, 512, 0, stream>>>(
            resin, in_w + (size_t)l*HH*2*EE, in_b + (size_t)l*2*EE,
            norm_w + (size_t)l*HH, xz);
        k_cbd<<<BT/8, 512, 0, stream>>>(
            xz, conv_w + (size_t)l*EE*KK, conv_b + (size_t)l*EE,
            pl_w + (size_t)l*EE*NJ, pl_b + (size_t)l*NJ,
            Wdt + (size_t)l*EE*EE, bdt + (size_t)l*EE,
            xcT, BC4, deltaT, sT);
        k_scan_local<<<BB*GG*(EE/2), 128, 0, stream>>>(
            BC4, deltaT, sT, A_log + (size_t)l*EE*HH, yT, hchain, dsum);
        k_scan_fix<<<BB*(GG-1)*(EE/2), 128, 0, stream>>>(
            BC4, deltaT, A_log + (size_t)l*EE*HH, hchain, dsum, yT);
        k_gate<<<BT/8, 256, 0, stream>>>(
            yT, xcT, xz, Dp + (size_t)l*EE,
            out_w + (size_t)l*EE*HH, out_b + (size_t)l*HH, resin, xres);
    }
    k_finalnorm<<<BT/8, 512, 0, stream>>>(xres, fnw, (float*)d_out);
}